// Round 1
// baseline (191.450 us; speedup 1.0000x reference)
//
#include <hip/hip_runtime.h>
#include <hip/hip_bf16.h>

#define NPROP 8192
#define SORT_THREADS 1024

__device__ __forceinline__ bool iou_gt_thr(float4 a, float4 b) {
    float areaA = (a.z - a.x) * (a.w - a.y);
    float areaB = (b.z - b.x) * (b.w - b.y);
    float lx = fmaxf(a.x, b.x), ly = fmaxf(a.y, b.y);
    float rx = fminf(a.z, b.z), ry = fminf(a.w, b.w);
    float w = fmaxf(rx - lx, 0.0f), h = fmaxf(ry - ly, 0.0f);
    float inter = w * h;
    float uni = areaA + areaB - inter;
    float iou = inter / fmaxf(uni, 1e-6f);
    return iou > 0.3f;
}

// K1: bitonic sort (score desc, idx asc) + gather + validity flags.
__global__ __launch_bounds__(SORT_THREADS)
void k_sort(const float* __restrict__ boxes, const float* __restrict__ scores,
            const float* __restrict__ img,
            float* __restrict__ s_sorted, float4* __restrict__ b_sorted,
            int* __restrict__ vflag) {
    __shared__ unsigned long long keys[NPROP]; // exactly 64 KiB
    const int tid = threadIdx.x;

    for (int p = tid; p < NPROP; p += SORT_THREADS) {
        float s = scores[p];
        unsigned sb = __float_as_uint(s); // positive floats: bit order == value order
        keys[p] = ((unsigned long long)sb << 32) |
                  (unsigned long long)(unsigned)(NPROP - 1 - p); // tie: smaller idx first
    }
    __syncthreads();

    for (int k = 2; k <= NPROP; k <<= 1) {
        for (int j = k >> 1; j > 0; j >>= 1) {
            for (int t = tid; t < NPROP / 2; t += SORT_THREADS) {
                int i = 2 * t - (t & (j - 1));
                int p = i + j;
                bool descDir = ((i & k) == 0);
                unsigned long long a = keys[i], c = keys[p];
                bool sw = descDir ? (a < c) : (a > c);
                if (sw) { keys[i] = c; keys[p] = a; }
            }
            __syncthreads();
        }
    }

    float ix1 = img[0], iy1 = img[1], ix2 = img[2], iy2 = img[3];
    float img_area = (ix2 - ix1) * (iy2 - iy1);
    for (int p = tid; p < NPROP; p += SORT_THREADS) {
        unsigned long long key = keys[p];
        int idx = NPROP - 1 - (int)(unsigned)(key & 0xffffffffULL);
        float s = __uint_as_float((unsigned)(key >> 32));
        float4 bx = reinterpret_cast<const float4*>(boxes)[idx];
        float w = bx.z - bx.x, h = bx.w - bx.y;
        float ratio = w / (h + 1e-12f);
        bool vs = (ratio > 0.25f) && (ratio < 4.0f);
        float lx = fmaxf(ix1, bx.x), ly = fmaxf(iy1, bx.y);
        float rx = fminf(ix2, bx.z), ry = fminf(iy2, bx.w);
        float iw = fmaxf(rx - lx, 0.0f), ih = fmaxf(ry - ly, 0.0f);
        float iof = (iw * ih) / fmaxf(img_area, 1e-6f);
        bool v = vs && (iof > 0.01f) && (s > 0.85f);
        s_sorted[p] = s;
        b_sorted[p] = bx;
        vflag[p] = v ? 1 : 0;
    }
}

// K2: compact valid subset (order-preserving) + blocked greedy NMS bitmask.
__global__ __launch_bounds__(SORT_THREADS)
void k_nms(const float4* __restrict__ b_sorted, const int* __restrict__ vflag,
           int* __restrict__ rank, float4* __restrict__ cbox,
           unsigned long long* __restrict__ removed_out, int* __restrict__ nvalid_out) {
    const int T = SORT_THREADS;
    const int tid = threadIdx.x;
    __shared__ int tsum[SORT_THREADS];
    __shared__ float4 rowbox[64];
    __shared__ unsigned long long diag[64];
    __shared__ unsigned long long removed[NPROP / 64]; // 128 words

    // --- prefix scan over validity flags (8 contiguous per thread) ---
    const int base = tid * 8;
    int f[8]; int tot = 0;
    #pragma unroll
    for (int u = 0; u < 8; u++) { f[u] = vflag[base + u]; tot += f[u]; }
    tsum[tid] = tot;
    __syncthreads();
    for (int off = 1; off < T; off <<= 1) {
        int x = (tid >= off) ? tsum[tid - off] : 0;
        __syncthreads();
        tsum[tid] += x;
        __syncthreads();
    }
    int incl = tsum[tid];
    int V = tsum[T - 1];
    int kk = incl - tot; // exclusive base
    #pragma unroll
    for (int u = 0; u < 8; u++) {
        int p = base + u;
        if (f[u]) { rank[p] = kk; cbox[kk] = b_sorted[p]; kk++; }
        else      { rank[p] = -1; }
    }
    // fallback: nothing valid -> keep only top-scoring (sorted pos 0)
    if (V == 0) {
        if (tid == 0) { rank[0] = 0; cbox[0] = b_sorted[0]; }
        V = 1;
    }
    const int W = (V + 63) / 64;
    // init removed: bits >= V pre-removed (padding never suppresses / never kept)
    for (int w = tid; w < NPROP / 64; w += T) {
        int b0 = w * 64;
        unsigned long long m;
        if (b0 >= V) m = ~0ULL;
        else if (b0 + 64 <= V) m = 0ULL;
        else m = (~0ULL) << (V - b0);
        removed[w] = m;
    }
    __syncthreads();

    const int wave = tid >> 6, lane = tid & 63;
    for (int b = 0; b < W; b++) {
        const int rb0 = b * 64;
        if (tid < 64) {
            int r = rb0 + tid;
            rowbox[tid] = (r < V) ? cbox[r] : make_float4(0.f, 0.f, 0.f, 0.f);
        }
        __syncthreads();
        // Phase A: intra-block suppression words
        for (int i = wave; i < 64; i += 16) {
            bool cond = false;
            int col = rb0 + lane;
            if (col < V && lane > i && (rb0 + i) < V)
                cond = iou_gt_thr(rowbox[i], rowbox[lane]);
            unsigned long long bal = __ballot(cond);
            if (lane == 0) diag[i] = bal;
        }
        __syncthreads();
        // Phase B: serial resolve within block
        if (tid == 0) {
            unsigned long long r = removed[b];
            #pragma unroll 1
            for (int i = 0; i < 64; i++)
                if (!((r >> i) & 1ULL)) r |= diag[i];
            removed[b] = r;
        }
        __syncthreads();
        // Phase C: apply surviving rows to all later column-words
        unsigned long long r = removed[b];
        unsigned long long keptm = ~r;
        for (int w = b + 1 + wave; w < W; w += 16) {
            int j = w * 64 + lane;
            bool sup = false;
            unsigned long long already = removed[w];
            if (j < V && !((already >> lane) & 1ULL)) {
                float4 bj = cbox[j];
                unsigned long long km = keptm;
                while (km) {
                    int i = __builtin_ctzll(km);
                    km &= km - 1;
                    if (iou_gt_thr(rowbox[i], bj)) { sup = true; break; }
                }
            }
            unsigned long long bal = __ballot(sup);
            if (lane == 0) removed[w] |= bal;
        }
        __syncthreads();
    }

    for (int w = tid; w < NPROP / 64; w += T) removed_out[w] = removed[w];
    if (tid == 0) nvalid_out[0] = V;
}

// K3: final output [N,5]*keep then keep mask as 0/1 floats.
__global__ void k_final(const float* __restrict__ s_sorted,
                        const float4* __restrict__ b_sorted,
                        const int* __restrict__ rank,
                        const unsigned long long* __restrict__ removed,
                        float* __restrict__ out) {
    int p = blockIdx.x * blockDim.x + threadIdx.x;
    if (p >= NPROP) return;
    int k = rank[p];
    bool keep = false;
    if (k >= 0) keep = !((removed[k >> 6] >> (k & 63)) & 1ULL);
    float m = keep ? 1.0f : 0.0f;
    float4 b = b_sorted[p];
    out[p * 5 + 0] = b.x * m;
    out[p * 5 + 1] = b.y * m;
    out[p * 5 + 2] = b.z * m;
    out[p * 5 + 3] = b.w * m;
    out[p * 5 + 4] = s_sorted[p] * m;
    out[NPROP * 5 + p] = m;
}

extern "C" void kernel_launch(void* const* d_in, const int* in_sizes, int n_in,
                              void* d_out, int out_size, void* d_ws, size_t ws_size,
                              hipStream_t stream) {
    const float* boxes  = (const float*)d_in[0];
    const float* scores = (const float*)d_in[1];
    const float* img    = (const float*)d_in[2];
    char* ws = (char*)d_ws;
    // ws layout (16B-aligned chunks):
    float4* b_sorted = (float4*)(ws + 0);        // 131072 B
    float4* cbox     = (float4*)(ws + 131072);   // 131072 B
    float*  s_sorted = (float*)(ws + 262144);    //  32768 B
    int*    vflag    = (int*)(ws + 294912);      //  32768 B
    int*    rank     = (int*)(ws + 327680);      //  32768 B
    unsigned long long* removed = (unsigned long long*)(ws + 360448); // 1024 B
    int*    nvalid   = (int*)(ws + 361472);      // 4 B
    float* out = (float*)d_out;

    k_sort<<<1, SORT_THREADS, 0, stream>>>(boxes, scores, img, s_sorted, b_sorted, vflag);
    k_nms<<<1, SORT_THREADS, 0, stream>>>(b_sorted, vflag, rank, cbox, removed, nvalid);
    k_final<<<32, 256, 0, stream>>>(s_sorted, b_sorted, rank, removed, out);
}

// Round 2
// 167.893 us; speedup vs baseline: 1.1403x; 1.1403x over previous
//
#include <hip/hip_runtime.h>
#include <hip/hip_bf16.h>

#define NPROP 8192
#define NT 1024

typedef unsigned long long u64;

__device__ __forceinline__ u64 umax64(u64 a, u64 b) { return a > b ? a : b; }
__device__ __forceinline__ u64 umin64(u64 a, u64 b) { return a < b ? a : b; }

__device__ __forceinline__ bool iou_gt_thr(float4 a, float4 b) {
    float areaA = (a.z - a.x) * (a.w - a.y);
    float areaB = (b.z - b.x) * (b.w - b.y);
    float lx = fmaxf(a.x, b.x), ly = fmaxf(a.y, b.y);
    float rx = fminf(a.z, b.z), ry = fminf(a.w, b.w);
    float w = fmaxf(rx - lx, 0.0f), h = fmaxf(ry - ly, 0.0f);
    float inter = w * h;
    float uni = areaA + areaB - inter;
    float iou = inter / fmaxf(uni, 1e-6f);
    return iou > 0.3f;
}

// in-register stage, J in {1,2,4}: all v[] indices compile-time (rule #20)
template<int J>
__device__ __forceinline__ void local_stage(u64 v[8], int tid, int kk) {
    #pragma unroll
    for (int s = 0; s < 8; s++) {
        if (!(s & J)) {
            int e = tid * 8 + s;
            bool desc = ((e & kk) == 0);
            u64 a = v[s], b = v[s | J];
            bool sw = desc ? (a < b) : (a > b);
            if (sw) { v[s] = b; v[s | J] = a; }
        }
    }
}

// cross-lane stage, 8 <= j <= 256 (lane distance j/8 <= 32, within wave64)
__device__ __forceinline__ void shfl_stage(u64 v[8], int tid, int j, int kk) {
    int pm = j >> 3;
    bool upper = (tid & pm) != 0;
    #pragma unroll
    for (int u = 0; u < 8; u++) {
        u64 o = __shfl_xor(v[u], pm, 64);
        int e = tid * 8 + u;
        bool takeMax = (((e & kk) == 0) != upper);
        v[u] = takeMax ? umax64(v[u], o) : umin64(v[u], o);
    }
}

// cross-wave stage, j >= 512, via LDS (transposed layout: 4-way conflict only)
__device__ __forceinline__ void lds_stage(u64* lk, u64 v[8], int tid, int j, int kk) {
    #pragma unroll
    for (int u = 0; u < 8; u++) lk[u * NT + tid] = v[u];
    __syncthreads();
    int pt = tid ^ (j >> 3);
    bool upper = (tid & (j >> 3)) != 0;
    #pragma unroll
    for (int u = 0; u < 8; u++) {
        u64 o = lk[u * NT + pt];
        int e = tid * 8 + u;
        bool takeMax = (((e & kk) == 0) != upper);
        v[u] = takeMax ? umax64(v[u], o) : umin64(v[u], o);
    }
    __syncthreads();
}

__global__ __launch_bounds__(NT)
void k_baron(const float* __restrict__ boxes, const float* __restrict__ scores,
             const float* __restrict__ img, float4* __restrict__ cbox,
             float* __restrict__ out) {
    __shared__ u64 lkeys[NPROP];           // 64 KiB (sort only)
    __shared__ float4 rowbox[64];
    __shared__ u64 diag[64];
    __shared__ u64 removed[NPROP / 64];
    __shared__ int wsum[16];
    __shared__ int wexcl[16];
    __shared__ int vtot;

    const int tid = threadIdx.x;
    const int lane = tid & 63, wave = tid >> 6;

    // ---- 1. build keys in registers: (score_bits<<32) | (N-1-idx) ----
    u64 v[8];
    const float4* s4 = reinterpret_cast<const float4*>(scores);
    float4 sa = s4[tid * 2], sb = s4[tid * 2 + 1];
    float ss[8] = {sa.x, sa.y, sa.z, sa.w, sb.x, sb.y, sb.z, sb.w};
    #pragma unroll
    for (int u = 0; u < 8; u++) {
        int p = tid * 8 + u;
        v[u] = ((u64)__float_as_uint(ss[u]) << 32) |
               (u64)(unsigned)(NPROP - 1 - p);
    }

    // ---- 2. hybrid bitonic sort (descending) ----
    for (int kk = 2; kk <= NPROP; kk <<= 1) {
        for (int j = kk >> 1; j >= 512; j >>= 1) lds_stage(lkeys, v, tid, j, kk);
        for (int j = ((kk >> 1) > 256 ? 256 : (kk >> 1)); j >= 8; j >>= 1)
            shfl_stage(v, tid, j, kk);
        if (kk >= 8) local_stage<4>(v, tid, kk);
        if (kk >= 4) local_stage<2>(v, tid, kk);
        local_stage<1>(v, tid, kk);
    }

    // ---- 3. extract idx/score, gather boxes, validity flags ----
    float ix1 = img[0], iy1 = img[1], ix2 = img[2], iy2 = img[3];
    float img_area = (ix2 - ix1) * (iy2 - iy1);
    float4 bx[8]; float sc[8]; int rnk[8]; bool vf[8]; int tot = 0;
    #pragma unroll
    for (int u = 0; u < 8; u++) {
        int idx = NPROP - 1 - (int)(unsigned)(v[u] & 0xffffffffu);
        sc[u] = __uint_as_float((unsigned)(v[u] >> 32));
        float4 b = reinterpret_cast<const float4*>(boxes)[idx];
        bx[u] = b;
        float w = b.z - b.x, h = b.w - b.y;
        float ratio = w / (h + 1e-12f);
        bool vs = (ratio > 0.25f) && (ratio < 4.0f);
        float lx = fmaxf(ix1, b.x), ly = fmaxf(iy1, b.y);
        float rx = fminf(ix2, b.z), ry = fminf(iy2, b.w);
        float iw = fmaxf(rx - lx, 0.0f), ih = fmaxf(ry - ly, 0.0f);
        float iof = (iw * ih) / fmaxf(img_area, 1e-6f);
        vf[u] = vs && (iof > 0.01f) && (sc[u] > 0.85f);
        tot += vf[u] ? 1 : 0;
    }

    // ---- 4. scan (wave shfl scan + tiny cross-wave scan) + compact ----
    int incl = tot;
    #pragma unroll
    for (int off = 1; off < 64; off <<= 1) {
        int n = __shfl_up(incl, off, 64);
        if (lane >= off) incl += n;
    }
    if (lane == 63) wsum[wave] = incl;
    __syncthreads();
    if (tid == 0) {
        int acc = 0;
        #pragma unroll
        for (int w = 0; w < 16; w++) { int t = wsum[w]; wexcl[w] = acc; acc += t; }
        vtot = acc;
    }
    __syncthreads();
    int V = vtot;
    int base = wexcl[wave] + (incl - tot);
    #pragma unroll
    for (int u = 0; u < 8; u++) {
        if (vf[u]) { rnk[u] = base; cbox[base] = bx[u]; base++; }
        else rnk[u] = -1;
    }
    if (V == 0) {               // fallback: keep top-scoring only
        if (tid == 0) { rnk[0] = 0; cbox[0] = bx[0]; }
        V = 1;
    }
    const int W = (V + 63) >> 6;
    for (int w = tid; w < NPROP / 64; w += NT) {
        int b0 = w * 64; u64 m;
        if (b0 >= V) m = ~0ull;
        else if (b0 + 64 <= V) m = 0ull;
        else m = (~0ull) << (V - b0);
        removed[w] = m;
    }
    __syncthreads();

    // ---- 5. blocked greedy NMS ----
    for (int b = 0; b < W; b++) {
        const int rb0 = b * 64;
        if (tid < 64) {
            int r = rb0 + tid;
            rowbox[tid] = (r < V) ? cbox[r] : make_float4(0.f, 0.f, 0.f, 0.f);
        }
        __syncthreads();
        float4 colbox = rowbox[lane];   // per-lane register copy (reused 4x)
        // Phase A: intra-block suppression ballots
        for (int i = wave; i < 64; i += 16) {
            bool cond = false;
            int col = rb0 + lane;
            if (col < V && lane > i && rb0 + i < V)
                cond = iou_gt_thr(rowbox[i], colbox);
            u64 bal = __ballot(cond);
            if (lane == 0) diag[i] = bal;
        }
        __syncthreads();
        // Phase B: serial resolve — diag in per-lane regs, readlane chain
        if (tid < 64) {
            u64 d = diag[tid];
            u64 r = removed[b];
            #pragma unroll
            for (int i = 0; i < 64; i++) {
                u64 di = __shfl(d, i, 64);
                r |= ((r >> i) & 1ull) ? 0ull : di;
            }
            if (tid == 0) removed[b] = r;
        }
        __syncthreads();
        // Phase C: apply kept rows to later words (pipelined OR, word skip)
        u64 keptm = ~removed[b];
        for (int w = b + 1 + wave; w < W; w += 16) {
            u64 already = removed[w];
            if (already == ~0ull) continue;
            int j = w * 64 + lane;
            float4 bj = cbox[j];
            bool sup = false;
            u64 km = keptm;
            while (km) {
                int i = __builtin_ctzll(km);
                km &= km - 1;
                sup = sup | iou_gt_thr(rowbox[i], bj);
            }
            u64 bal = __ballot(sup);
            if (lane == 0) removed[w] |= bal;
        }
        __syncthreads();
    }

    // ---- 6. final output from registers ----
    #pragma unroll
    for (int u = 0; u < 8; u++) {
        int p = tid * 8 + u;
        int k = rnk[u];
        bool keep = (k >= 0) && !((removed[k >> 6] >> (k & 63)) & 1ull);
        float m = keep ? 1.0f : 0.0f;
        out[p * 5 + 0] = bx[u].x * m;
        out[p * 5 + 1] = bx[u].y * m;
        out[p * 5 + 2] = bx[u].z * m;
        out[p * 5 + 3] = bx[u].w * m;
        out[p * 5 + 4] = sc[u] * m;
        out[NPROP * 5 + p] = m;
    }
}

extern "C" void kernel_launch(void* const* d_in, const int* in_sizes, int n_in,
                              void* d_out, int out_size, void* d_ws, size_t ws_size,
                              hipStream_t stream) {
    const float* boxes  = (const float*)d_in[0];
    const float* scores = (const float*)d_in[1];
    const float* img    = (const float*)d_in[2];
    float4* cbox = (float4*)d_ws;       // (8192+64)*16 B
    float* out = (float*)d_out;
    k_baron<<<1, NT, 0, stream>>>(boxes, scores, img, cbox, out);
}

// Round 4
// 127.786 us; speedup vs baseline: 1.4982x; 1.3139x over previous
//
#include <hip/hip_runtime.h>

#define NPROP 8192
#define NT 1024
typedef unsigned long long u64;

__device__ __forceinline__ int bucket_of(float s) {
    int b = (int)(s * 8192.0f);   // exact: *2^13 is an exponent shift
    return b < 0 ? 0 : (b > NPROP - 1 ? NPROP - 1 : b);
}

__device__ __forceinline__ bool iou_gt_thr(float4 a, float4 b) {
    float areaA = (a.z - a.x) * (a.w - a.y);
    float areaB = (b.z - b.x) * (b.w - b.y);
    float lx = fmaxf(a.x, b.x), ly = fmaxf(a.y, b.y);
    float rx = fminf(a.z, b.z), ry = fminf(a.w, b.w);
    float w = fmaxf(rx - lx, 0.0f), h = fmaxf(ry - ly, 0.0f);
    float inter = w * h;
    float uni = areaA + areaB - inter;
    float iou = inter / fmaxf(uni, 1e-6f);
    return iou > 0.3f;
}

// K1: bucket histogram
__global__ void k_hist(const float* __restrict__ scores, int* __restrict__ hist) {
    int i = blockIdx.x * blockDim.x + threadIdx.x;
    if (i < NPROP) atomicAdd(&hist[bucket_of(scores[i])], 1);
}

// K2: exclusive prefix over 8192 bucket counts (written twice: ro + allocator)
__global__ __launch_bounds__(NT)
void k_scan(const int* __restrict__ hist, int* __restrict__ pref_ex,
            int* __restrict__ pref_mut) {
    __shared__ int wsum[16], wexcl[16];
    int tid = threadIdx.x, lane = tid & 63, wave = tid >> 6;
    int h[8]; int tot = 0;
    #pragma unroll
    for (int u = 0; u < 8; u++) { h[u] = hist[tid * 8 + u]; tot += h[u]; }
    int incl = tot;
    #pragma unroll
    for (int off = 1; off < 64; off <<= 1) {
        int n = __shfl_up(incl, off, 64);
        if (lane >= off) incl += n;
    }
    if (lane == 63) wsum[wave] = incl;
    __syncthreads();
    if (tid == 0) {
        int acc = 0;
        #pragma unroll
        for (int w = 0; w < 16; w++) { int t = wsum[w]; wexcl[w] = acc; acc += t; }
    }
    __syncthreads();
    int run = wexcl[wave] + (incl - tot);
    #pragma unroll
    for (int u = 0; u < 8; u++) {
        pref_ex[tid * 8 + u] = run;
        pref_mut[tid * 8 + u] = run;
        run += h[u];
    }
}

// K3: scatter into bucket-grouped order (in-bucket order arbitrary; fixed by K4)
__global__ void k_scatter(const float* __restrict__ scores, int* __restrict__ pref_mut,
                          int* __restrict__ tmp_idx) {
    int i = blockIdx.x * blockDim.x + threadIdx.x;
    if (i < NPROP) {
        int slot = atomicAdd(&pref_mut[bucket_of(scores[i])], 1);
        tmp_idx[slot] = i;
    }
}

// K4: exact stable rank via in-bucket counting + validity; build sorted arrays
__global__ void k_rank(const float* __restrict__ scores, const float* __restrict__ boxes,
                       const float* __restrict__ img,
                       const int* __restrict__ tmp_idx, const int* __restrict__ pref_ex,
                       const int* __restrict__ pref_mut,
                       float4* __restrict__ srt_box, float* __restrict__ srt_sv) {
    int p = blockIdx.x * blockDim.x + threadIdx.x;
    if (p >= NPROP) return;
    int i = tmp_idx[p];
    float s = scores[i];
    u64 key = ((u64)__float_as_uint(s) << 32) | (u64)(unsigned)(NPROP - 1 - i);
    int b = bucket_of(s);
    int lo = pref_ex[b], hi = pref_mut[b];   // post-K3 pref_mut[b] == bucket end
    int cnt = 0;
    for (int q = lo; q < hi; q++) {
        int j = tmp_idx[q];
        u64 kj = ((u64)__float_as_uint(scores[j]) << 32) | (u64)(unsigned)(NPROP - 1 - j);
        cnt += (kj < key) ? 1 : 0;
    }
    int rank = NPROP - 1 - (lo + cnt);       // descending, stable (idx tiebreak in key)
    float4 bx = reinterpret_cast<const float4*>(boxes)[i];
    float ix1 = img[0], iy1 = img[1], ix2 = img[2], iy2 = img[3];
    float img_area = (ix2 - ix1) * (iy2 - iy1);
    float w = bx.z - bx.x, hh = bx.w - bx.y;
    float ratio = w / (hh + 1e-12f);
    bool vs = (ratio > 0.25f) && (ratio < 4.0f);
    float lx = fmaxf(ix1, bx.x), ly = fmaxf(iy1, bx.y);
    float rx = fminf(ix2, bx.z), ry = fminf(iy2, bx.w);
    float iw = fmaxf(rx - lx, 0.0f), ih = fmaxf(ry - ly, 0.0f);
    float iof = (iw * ih) / fmaxf(img_area, 1e-6f);
    bool vf = vs && (iof > 0.01f) && (s > 0.85f);
    srt_box[rank] = bx;
    srt_sv[rank] = __uint_as_float(__float_as_uint(s) | (vf ? 0x80000000u : 0u));
}

// K5: compact valid subset + blocked greedy NMS + vectorized output
__global__ __launch_bounds__(NT)
void k_nms(const float4* __restrict__ srt_box, const float* __restrict__ srt_sv,
           float4* __restrict__ cbox, float* __restrict__ out) {
    __shared__ float4 rowbox[64];
    __shared__ u64 diag[64];
    __shared__ u64 removed[NPROP / 64];
    __shared__ int wsum[16], wexcl[16];
    __shared__ int vtot;

    const int tid = threadIdx.x, lane = tid & 63, wave = tid >> 6;

    float4 bx[8]; float sc[8]; bool vf[8]; int rnk[8]; int tot = 0;
    #pragma unroll
    for (int u = 0; u < 8; u++) {
        int p = tid * 8 + u;
        bx[u] = srt_box[p];
        unsigned svb = __float_as_uint(srt_sv[p]);
        vf[u] = (svb >> 31) != 0;
        sc[u] = __uint_as_float(svb & 0x7fffffffu);
        tot += vf[u] ? 1 : 0;
    }

    // scan + compact (order-preserving)
    int incl = tot;
    #pragma unroll
    for (int off = 1; off < 64; off <<= 1) {
        int n = __shfl_up(incl, off, 64);
        if (lane >= off) incl += n;
    }
    if (lane == 63) wsum[wave] = incl;
    __syncthreads();
    if (tid == 0) {
        int acc = 0;
        #pragma unroll
        for (int w = 0; w < 16; w++) { int t = wsum[w]; wexcl[w] = acc; acc += t; }
        vtot = acc;
    }
    __syncthreads();
    int V = vtot;
    int base = wexcl[wave] + (incl - tot);
    #pragma unroll
    for (int u = 0; u < 8; u++) {
        if (vf[u]) { rnk[u] = base; cbox[base] = bx[u]; base++; }
        else rnk[u] = -1;
    }
    if (V == 0) {               // fallback: keep top-scoring only
        if (tid == 0) { rnk[0] = 0; cbox[0] = bx[0]; }
        V = 1;
    }
    const int W = (V + 63) >> 6;
    for (int w = tid; w < NPROP / 64; w += NT) {
        int b0 = w * 64; u64 m;
        if (b0 >= V) m = ~0ull;
        else if (b0 + 64 <= V) m = 0ull;
        else m = (~0ull) << (V - b0);
        removed[w] = m;
    }
    __syncthreads();

    for (int b = 0; b < W; b++) {
        const int rb0 = b * 64;
        if (tid < 64) {
            int r = rb0 + tid;
            rowbox[tid] = (r < V) ? cbox[r] : make_float4(0.f, 0.f, 0.f, 0.f);
        }
        __syncthreads();
        float4 colbox = rowbox[lane];
        // Phase A: intra-block suppression ballots
        for (int i = wave; i < 64; i += 16) {
            bool cond = false;
            int col = rb0 + lane;
            if (col < V && lane > i && rb0 + i < V)
                cond = iou_gt_thr(rowbox[i], colbox);
            u64 bal = __ballot(cond);
            if (lane == 0) diag[i] = bal;
        }
        __syncthreads();
        // Phase B: serial resolve (wave 0, readlane chain)
        if (tid < 64) {
            u64 d = diag[tid];
            u64 r = removed[b];
            #pragma unroll
            for (int i = 0; i < 64; i++) {
                u64 di = __shfl(d, i, 64);
                r |= ((r >> i) & 1ull) ? 0ull : di;
            }
            if (tid == 0) removed[b] = r;
        }
        __syncthreads();
        // Phase C: apply kept rows to later words
        u64 keptm = ~removed[b];
        for (int w = b + 1 + wave; w < W; w += 16) {
            u64 already = removed[w];
            if (already == ~0ull) continue;
            int j = w * 64 + lane;
            float4 bj = cbox[j];
            bool sup = false;
            u64 km = keptm;
            while (km) {
                int i = __builtin_ctzll(km);
                km &= km - 1;
                sup = sup | iou_gt_thr(rowbox[i], bj);
            }
            u64 bal = __ballot(sup);
            if (lane == 0) removed[w] |= bal;
        }
        __syncthreads();
    }

    // vectorized output: 10 float4 (boxes+scores) + 2 float4 (mask) per thread
    float ob[40]; float om[8];
    #pragma unroll
    for (int u = 0; u < 8; u++) {
        int k = rnk[u];
        bool keep = (k >= 0) && !((removed[k >> 6] >> (k & 63)) & 1ull);
        float m = keep ? 1.0f : 0.0f;
        ob[u * 5 + 0] = bx[u].x * m;
        ob[u * 5 + 1] = bx[u].y * m;
        ob[u * 5 + 2] = bx[u].z * m;
        ob[u * 5 + 3] = bx[u].w * m;
        ob[u * 5 + 4] = sc[u] * m;
        om[u] = m;
    }
    float4* o4 = reinterpret_cast<float4*>(out) + tid * 10;
    #pragma unroll
    for (int q = 0; q < 10; q++)
        o4[q] = make_float4(ob[q * 4 + 0], ob[q * 4 + 1], ob[q * 4 + 2], ob[q * 4 + 3]);
    float4* m4 = reinterpret_cast<float4*>(out + NPROP * 5) + tid * 2;
    m4[0] = make_float4(om[0], om[1], om[2], om[3]);
    m4[1] = make_float4(om[4], om[5], om[6], om[7]);
}

extern "C" void kernel_launch(void* const* d_in, const int* in_sizes, int n_in,
                              void* d_out, int out_size, void* d_ws, size_t ws_size,
                              hipStream_t stream) {
    const float* boxes  = (const float*)d_in[0];
    const float* scores = (const float*)d_in[1];
    const float* img    = (const float*)d_in[2];
    char* ws = (char*)d_ws;
    int*    hist     = (int*)(ws + 0);        // 32 KiB
    int*    pref_ex  = (int*)(ws + 32768);    // 32 KiB
    int*    pref_mut = (int*)(ws + 65536);    // 32 KiB
    int*    tmp_idx  = (int*)(ws + 98304);    // 32 KiB
    float*  srt_sv   = (float*)(ws + 131072); // 32 KiB
    float4* srt_box  = (float4*)(ws + 163840);// 128 KiB
    float4* cbox     = (float4*)(ws + 294912);// 128 KiB
    float* out = (float*)d_out;

    hipMemsetAsync(hist, 0, NPROP * sizeof(int), stream);
    k_hist<<<32, 256, 0, stream>>>(scores, hist);
    k_scan<<<1, NT, 0, stream>>>(hist, pref_ex, pref_mut);
    k_scatter<<<32, 256, 0, stream>>>(scores, pref_mut, tmp_idx);
    k_rank<<<32, 256, 0, stream>>>(scores, boxes, img, tmp_idx, pref_ex, pref_mut,
                                   srt_box, srt_sv);
    k_nms<<<1, NT, 0, stream>>>(srt_box, srt_sv, cbox, out);
}

// Round 6
// 81.690 us; speedup vs baseline: 2.3436x; 1.5643x over previous
//
#include <hip/hip_runtime.h>

#define NPROP 8192
#define NT 1024
typedef unsigned long long u64;

__device__ __forceinline__ int bucket_of(float s) {
    int b = (int)(s * 8192.0f);
    return b < 0 ? 0 : (b > NPROP - 1 ? NPROP - 1 : b);
}

__device__ __forceinline__ bool iou_gt_thr(float4 a, float4 b) {
    float areaA = (a.z - a.x) * (a.w - a.y);
    float areaB = (b.z - b.x) * (b.w - b.y);
    float lx = fmaxf(a.x, b.x), ly = fmaxf(a.y, b.y);
    float rx = fminf(a.z, b.z), ry = fminf(a.w, b.w);
    float w = fmaxf(rx - lx, 0.0f), h = fmaxf(ry - ly, 0.0f);
    float inter = w * h;
    float uni = areaA + areaB - inter;
    float iou = inter / fmaxf(uni, 1e-6f);
    return iou > 0.3f;
}

// K1: bucket histogram
__global__ void k_hist(const float* __restrict__ scores, int* __restrict__ hist) {
    int i = blockIdx.x * blockDim.x + threadIdx.x;
    if (i < NPROP) atomicAdd(&hist[bucket_of(scores[i])], 1);
}

// K2: exclusive prefix over 8192 bucket counts
__global__ __launch_bounds__(NT)
void k_scan(const int* __restrict__ hist, int* __restrict__ pref_ex,
            int* __restrict__ pref_mut) {
    __shared__ int wsum[16], wexcl[16];
    int tid = threadIdx.x, lane = tid & 63, wave = tid >> 6;
    int h[8]; int tot = 0;
    #pragma unroll
    for (int u = 0; u < 8; u++) { h[u] = hist[tid * 8 + u]; tot += h[u]; }
    int incl = tot;
    #pragma unroll
    for (int off = 1; off < 64; off <<= 1) {
        int n = __shfl_up(incl, off, 64);
        if (lane >= off) incl += n;
    }
    if (lane == 63) wsum[wave] = incl;
    __syncthreads();
    if (tid == 0) {
        int acc = 0;
        #pragma unroll
        for (int w = 0; w < 16; w++) { int t = wsum[w]; wexcl[w] = acc; acc += t; }
    }
    __syncthreads();
    int run = wexcl[wave] + (incl - tot);
    #pragma unroll
    for (int u = 0; u < 8; u++) {
        pref_ex[tid * 8 + u] = run;
        pref_mut[tid * 8 + u] = run;
        run += h[u];
    }
}

// K3: scatter into bucket-grouped order
__global__ void k_scatter(const float* __restrict__ scores, int* __restrict__ pref_mut,
                          int* __restrict__ tmp_idx) {
    int i = blockIdx.x * blockDim.x + threadIdx.x;
    if (i < NPROP) {
        int slot = atomicAdd(&pref_mut[bucket_of(scores[i])], 1);
        tmp_idx[slot] = i;
    }
}

// K4: exact stable rank via in-bucket counting + validity
__global__ void k_rank(const float* __restrict__ scores, const float* __restrict__ boxes,
                       const float* __restrict__ img,
                       const int* __restrict__ tmp_idx, const int* __restrict__ pref_ex,
                       const int* __restrict__ pref_mut,
                       float4* __restrict__ srt_box, float* __restrict__ srt_sv) {
    int p = blockIdx.x * blockDim.x + threadIdx.x;
    if (p >= NPROP) return;
    int i = tmp_idx[p];
    float s = scores[i];
    u64 key = ((u64)__float_as_uint(s) << 32) | (u64)(unsigned)(NPROP - 1 - i);
    int b = bucket_of(s);
    int lo = pref_ex[b], hi = pref_mut[b];
    int cnt = 0;
    for (int q = lo; q < hi; q++) {
        int j = tmp_idx[q];
        u64 kj = ((u64)__float_as_uint(scores[j]) << 32) | (u64)(unsigned)(NPROP - 1 - j);
        cnt += (kj < key) ? 1 : 0;
    }
    int rank = NPROP - 1 - (lo + cnt);
    float4 bx = reinterpret_cast<const float4*>(boxes)[i];
    float ix1 = img[0], iy1 = img[1], ix2 = img[2], iy2 = img[3];
    float img_area = (ix2 - ix1) * (iy2 - iy1);
    float w = bx.z - bx.x, hh = bx.w - bx.y;
    float ratio = w / (hh + 1e-12f);
    bool vs = (ratio > 0.25f) && (ratio < 4.0f);
    float lx = fmaxf(ix1, bx.x), ly = fmaxf(iy1, bx.y);
    float rx = fminf(ix2, bx.z), ry = fminf(iy2, bx.w);
    float iw = fmaxf(rx - lx, 0.0f), ih = fmaxf(ry - ly, 0.0f);
    float iof = (iw * ih) / fmaxf(img_area, 1e-6f);
    bool vf = vs && (iof > 0.01f) && (s > 0.85f);
    srt_box[rank] = bx;
    srt_sv[rank] = __uint_as_float(__float_as_uint(s) | (vf ? 0x80000000u : 0u));
}

// K5: compact valid subset (scan over sorted order) + V/W meta
__global__ __launch_bounds__(NT)
void k_compact(const float4* __restrict__ srt_box, const float* __restrict__ srt_sv,
               float4* __restrict__ cbox, int* __restrict__ crank,
               int* __restrict__ meta) {
    __shared__ int wsum[16], wexcl[16];
    const int tid = threadIdx.x, lane = tid & 63, wave = tid >> 6;
    bool vf[8]; int tot = 0;
    float4 bx[8];
    #pragma unroll
    for (int u = 0; u < 8; u++) {
        int p = tid * 8 + u;
        bx[u] = srt_box[p];
        vf[u] = (__float_as_uint(srt_sv[p]) >> 31) != 0;
        tot += vf[u] ? 1 : 0;
    }
    int incl = tot;
    #pragma unroll
    for (int off = 1; off < 64; off <<= 1) {
        int n = __shfl_up(incl, off, 64);
        if (lane >= off) incl += n;
    }
    if (lane == 63) wsum[wave] = incl;
    __syncthreads();
    if (tid == 0) {
        int acc = 0;
        #pragma unroll
        for (int w = 0; w < 16; w++) { int t = wsum[w]; wexcl[w] = acc; acc += t; }
        int V = acc == 0 ? 1 : acc;
        meta[0] = V;
        meta[1] = (V + 63) >> 6;
        meta[2] = acc;              // raw count (0 => fallback)
    }
    __syncthreads();
    int base = wexcl[wave] + (incl - tot);
    #pragma unroll
    for (int u = 0; u < 8; u++) {
        int p = tid * 8 + u;
        if (vf[u]) { crank[p] = base; cbox[base] = bx[u]; base++; }
        else crank[p] = -1;
    }
    if (meta[2] == 0 && tid == 0) { crank[0] = 0; cbox[0] = srt_box[0]; }
}

// K6: suppression mask matrix — wave per row, lane per column, ballot per word
__global__ __launch_bounds__(256)
void k_mask(const float4* __restrict__ cbox, const int* __restrict__ meta,
            u64* __restrict__ mask) {
    const int V = meta[0], W = meta[1];
    const int lane = threadIdx.x & 63;
    int gw = blockIdx.x * 4 + (threadIdx.x >> 6);
    for (int r = gw; r < V; r += 1024) {
        float4 br = cbox[r];
        for (int w = (r >> 6); w < W; w++) {
            int col = w * 64 + lane;
            bool ok = (col < V) && (col > r) && iou_gt_thr(br, cbox[col]);
            u64 bal = __ballot(ok);
            if (lane == 0) mask[(u64)r * W + w] = bal;
        }
    }
}

// K7: serial greedy resolve using precomputed masks (1 block)
__global__ __launch_bounds__(NT)
void k_resolve(const u64* __restrict__ mask, const int* __restrict__ meta,
               u64* __restrict__ remG) {
    __shared__ u64 rem[NPROP / 64];
    const int V = meta[0], W = meta[1];
    const int tid = threadIdx.x, lane = tid & 63, wave = tid >> 6;

    for (int w = tid; w < NPROP / 64; w += NT) {
        int b0 = w * 64; u64 m;
        if (b0 >= V) m = ~0ull;
        else if (b0 + 64 <= V) m = 0ull;
        else m = (~0ull) << (V - b0);
        rem[w] = m;
    }
    __syncthreads();

    for (int b = 0; b < W; b++) {
        const int rb0 = b * 64;
        // Phase B: intra-block resolve, scalar readlane chain (no LDS in chain)
        if (tid < 64) {
            int row = rb0 + tid;
            u64 d = (row < V) ? mask[(u64)row * W + b] : 0ull;
            unsigned dl0 = (unsigned)(d & 0xffffffffull);
            unsigned dh0 = (unsigned)(d >> 32);
            u64 r = rem[b];
            #pragma unroll
            for (int i = 0; i < 64; i++) {
                unsigned dl = (unsigned)__builtin_amdgcn_readlane((int)dl0, i);
                unsigned dh = (unsigned)__builtin_amdgcn_readlane((int)dh0, i);
                u64 di = ((u64)dh << 32) | (u64)dl;
                r |= ((r >> i) & 1ull) ? 0ull : di;
            }
            if (tid == 0) rem[b] = r;
        }
        __syncthreads();
        // Apply: kept rows OR their mask words into rem (parallel, no dep chains)
        u64 keptm = ~rem[b];
        #pragma unroll
        for (int t = 0; t < 4; t++) {
            int rl = wave * 4 + t;
            int row = rb0 + rl;
            if (row < V && ((keptm >> rl) & 1ull)) {
                for (int w = b + 1 + lane; w < W; w += 64) {
                    u64 m = mask[(u64)row * W + w];
                    if (m) atomicOr((unsigned long long*)&rem[w], m);
                }
            }
        }
        __syncthreads();
    }

    for (int w = tid; w < NPROP / 64; w += NT) remG[w] = rem[w];
}

// K8: final output [N,5]*keep + keep mask, vectorized float4 stores
__global__ __launch_bounds__(256)
void k_out(const float4* __restrict__ srt_box, const float* __restrict__ srt_sv,
           const int* __restrict__ crank, const u64* __restrict__ remG,
           float* __restrict__ out) {
    int tid = blockIdx.x * 256 + threadIdx.x;   // 0..1023, 8 positions each
    float ob[40]; float om[8];
    #pragma unroll
    for (int u = 0; u < 8; u++) {
        int p = tid * 8 + u;
        float4 b = srt_box[p];
        unsigned svb = __float_as_uint(srt_sv[p]);
        float s = __uint_as_float(svb & 0x7fffffffu);
        int k = crank[p];
        bool keep = (k >= 0) && !((remG[k >> 6] >> (k & 63)) & 1ull);
        float m = keep ? 1.0f : 0.0f;
        ob[u * 5 + 0] = b.x * m;
        ob[u * 5 + 1] = b.y * m;
        ob[u * 5 + 2] = b.z * m;
        ob[u * 5 + 3] = b.w * m;
        ob[u * 5 + 4] = s * m;
        om[u] = m;
    }
    float4* o4 = reinterpret_cast<float4*>(out) + tid * 10;
    #pragma unroll
    for (int q = 0; q < 10; q++)
        o4[q] = make_float4(ob[q * 4 + 0], ob[q * 4 + 1], ob[q * 4 + 2], ob[q * 4 + 3]);
    float4* m4 = reinterpret_cast<float4*>(out + NPROP * 5) + tid * 2;
    m4[0] = make_float4(om[0], om[1], om[2], om[3]);
    m4[1] = make_float4(om[4], om[5], om[6], om[7]);
}

extern "C" void kernel_launch(void* const* d_in, const int* in_sizes, int n_in,
                              void* d_out, int out_size, void* d_ws, size_t ws_size,
                              hipStream_t stream) {
    const float* boxes  = (const float*)d_in[0];
    const float* scores = (const float*)d_in[1];
    const float* img    = (const float*)d_in[2];
    char* ws = (char*)d_ws;
    int*    hist     = (int*)(ws + 0);         // 32 KiB
    int*    pref_ex  = (int*)(ws + 32768);     // 32 KiB
    int*    pref_mut = (int*)(ws + 65536);     // 32 KiB
    int*    tmp_idx  = (int*)(ws + 98304);     // 32 KiB
    float*  srt_sv   = (float*)(ws + 131072);  // 32 KiB
    float4* srt_box  = (float4*)(ws + 163840); // 128 KiB
    float4* cbox     = (float4*)(ws + 294912); // 128 KiB
    int*    crank    = (int*)(ws + 425984);    // 32 KiB
    u64*    remG     = (u64*)(ws + 458752);    // 1 KiB
    int*    meta     = (int*)(ws + 459776);    // 16 B
    u64*    mask     = (u64*)(ws + 460800);    // V*W*8 B (realistic ~150-300 KiB)
    float* out = (float*)d_out;

    hipMemsetAsync(hist, 0, NPROP * sizeof(int), stream);
    k_hist<<<32, 256, 0, stream>>>(scores, hist);
    k_scan<<<1, NT, 0, stream>>>(hist, pref_ex, pref_mut);
    k_scatter<<<32, 256, 0, stream>>>(scores, pref_mut, tmp_idx);
    k_rank<<<32, 256, 0, stream>>>(scores, boxes, img, tmp_idx, pref_ex, pref_mut,
                                   srt_box, srt_sv);
    k_compact<<<1, NT, 0, stream>>>(srt_box, srt_sv, cbox, crank, meta);
    k_mask<<<256, 256, 0, stream>>>(cbox, meta, mask);
    k_resolve<<<1, NT, 0, stream>>>(mask, meta, remG);
    k_out<<<4, 256, 0, stream>>>(srt_box, srt_sv, crank, remG, out);
}